// Round 1
// baseline (145.771 us; speedup 1.0000x reference)
//
#include <hip/hip_runtime.h>
#include <hip/hip_bf16.h>
#include <math.h>

#define D_DIM 4096

// LDS bank-conflict swizzle: XOR bits 2-4 with bits 7-9 of the word index.
// Involution, keeps 4-word (16B) blocks contiguous & aligned, and makes all
// three access patterns (stride-256, stride-16, contiguous-16) <=2-way
// conflicting (2-way is free on wave64 LDS).
__device__ __forceinline__ int swz(int i) {
    return i ^ (((i >> 7) & 7) << 2);
}

// In-register FWHT over 4 index bits (16 values). Unnormalized butterflies:
// (a,b) -> (a+b, a-b), matching the reference stage orientation.
__device__ __forceinline__ void radix16(float v[16]) {
#pragma unroll
    for (int b = 0; b < 4; ++b) {
#pragma unroll
        for (int i = 0; i < 16; ++i) {
            if (!(i & (1 << b))) {
                const int j = i | (1 << b);
                const float a = v[i];
                const float c = v[j];
                v[i] = a + c;
                v[j] = a - c;
            }
        }
    }
}

__global__ void compute_u_kernel(const float* __restrict__ g_mu,
                                 const float* __restrict__ g_rho,
                                 const float* __restrict__ eps,
                                 float* __restrict__ u) {
    const int i = blockIdx.x * blockDim.x + threadIdx.x;
    if (i < D_DIM) {
        const float r = g_rho[i];
        const float sp = (r > 20.0f) ? r : log1pf(expf(r));  // softplus
        u[i] = g_mu[i] + sp * eps[i];
    }
}

__global__ __launch_bounds__(256) void whvi_kernel(const float* __restrict__ x,
                                                   const float* __restrict__ s1,
                                                   const float* __restrict__ s2,
                                                   const float* __restrict__ u,
                                                   float* __restrict__ out) {
    __shared__ float lds[D_DIM];
    const int t = threadIdx.x;
    const int row = blockIdx.x;
    const float* __restrict__ xr = x + (size_t)row * D_DIM;

    float v[16];

    // ---- Phase 0: coalesced global load * s2, FWHT bits 8-11, write LDS ----
#pragma unroll
    for (int k = 0; k < 16; ++k) {
        const int idx = t + (k << 8);
        v[k] = xr[idx] * s2[idx];
    }
    radix16(v);
#pragma unroll
    for (int k = 0; k < 16; ++k) {
        lds[swz(t + (k << 8))] = v[k];
    }
    __syncthreads();

    // ---- Phase 1: FWHT bits 4-7 (in-place per thread; no intra-phase hazard) ----
    {
        const int base = ((t >> 4) << 8) | (t & 15);
#pragma unroll
        for (int k = 0; k < 16; ++k) v[k] = lds[swz(base | (k << 4))];
        radix16(v);
#pragma unroll
        for (int k = 0; k < 16; ++k) lds[swz(base | (k << 4))] = v[k];
    }
    __syncthreads();

    // ---- Phase 2: FWHT bits 0-3, * u, FWHT bits 0-3 (fused) ----
    {
        const int base = t << 4;
#pragma unroll
        for (int j = 0; j < 4; ++j) {
            const float4 r = *reinterpret_cast<const float4*>(&lds[swz(base + 4 * j)]);
            v[4 * j + 0] = r.x;
            v[4 * j + 1] = r.y;
            v[4 * j + 2] = r.z;
            v[4 * j + 3] = r.w;
        }
        radix16(v);
#pragma unroll
        for (int j = 0; j < 4; ++j) {
            const float4 uv = *reinterpret_cast<const float4*>(&u[base + 4 * j]);
            v[4 * j + 0] *= uv.x;
            v[4 * j + 1] *= uv.y;
            v[4 * j + 2] *= uv.z;
            v[4 * j + 3] *= uv.w;
        }
        radix16(v);
#pragma unroll
        for (int j = 0; j < 4; ++j) {
            const float4 r = make_float4(v[4 * j + 0], v[4 * j + 1], v[4 * j + 2], v[4 * j + 3]);
            *reinterpret_cast<float4*>(&lds[swz(base + 4 * j)]) = r;
        }
    }
    __syncthreads();

    // ---- Phase 3: FWHT bits 4-7 ----
    {
        const int base = ((t >> 4) << 8) | (t & 15);
#pragma unroll
        for (int k = 0; k < 16; ++k) v[k] = lds[swz(base | (k << 4))];
        radix16(v);
#pragma unroll
        for (int k = 0; k < 16; ++k) lds[swz(base | (k << 4))] = v[k];
    }
    __syncthreads();

    // ---- Phase 4: FWHT bits 8-11, * s1/sqrt(D), coalesced store ----
#pragma unroll
    for (int k = 0; k < 16; ++k) {
        v[k] = lds[swz(t + (k << 8))];
    }
    radix16(v);
    float* __restrict__ orow = out + (size_t)row * D_DIM;
#pragma unroll
    for (int k = 0; k < 16; ++k) {
        const int idx = t + (k << 8);
        orow[idx] = v[k] * s1[idx] * 0.015625f;  // 1/sqrt(4096) = 1/64
    }
}

extern "C" void kernel_launch(void* const* d_in, const int* in_sizes, int n_in,
                              void* d_out, int out_size, void* d_ws, size_t ws_size,
                              hipStream_t stream) {
    const float* x     = (const float*)d_in[0];
    const float* s1    = (const float*)d_in[1];
    const float* s2    = (const float*)d_in[2];
    const float* g_mu  = (const float*)d_in[3];
    const float* g_rho = (const float*)d_in[4];
    const float* eps   = (const float*)d_in[5];
    // d_in[6] = H : not needed (H is the standard Sylvester-Hadamard matrix,
    // realized implicitly by the FWHT butterflies).

    float* u = (float*)d_ws;  // D floats of scratch
    float* out = (float*)d_out;

    const int N = in_sizes[0] / D_DIM;

    compute_u_kernel<<<(D_DIM + 255) / 256, 256, 0, stream>>>(g_mu, g_rho, eps, u);
    whvi_kernel<<<N, 256, 0, stream>>>(x, s1, s2, u, out);
}

// Round 2
// 138.261 us; speedup vs baseline: 1.0543x; 1.0543x over previous
//
#include <hip/hip_runtime.h>
#include <math.h>

#define D_DIM 4096

typedef float v2f __attribute__((ext_vector_type(2)));

// Rank-complete LDS swizzle: XOR high bits into bank bits [4:2].
//   b2 ^= b5 ^ b11 ; b3 ^= b6 ^ b9 ; b4 ^= b7 ^ b8 ^ b10
// Verified by GF(2) rank analysis: all three access patterns used below
// (stride-256: m<<8|t ; stride-16: (t>>4)<<8|m<<4|(t&15) ; contiguous b128:
// t<<4|q) resolve to <=2-way bank aliasing on wave64 (2-way is free).
// Bits [1:0] untouched -> float4 contiguity & 16B alignment preserved.
__device__ __forceinline__ int swz(int i) {
    const int x2 = ((i >> 5) ^ (i >> 11)) & 1;
    const int x3 = ((i >> 6) ^ (i >> 9)) & 1;
    const int x4 = ((i >> 7) ^ (i >> 8) ^ (i >> 10)) & 1;
    return i ^ (x2 << 2) ^ (x3 << 3) ^ (x4 << 4);
}

// ---- packed-f32 butterfly primitives (VOP3P) ----
// bfly0: d = (a.x + a.y, a.x - a.y)  -- one instruction for a bit-0 butterfly.
__device__ __forceinline__ v2f bfly0(v2f a) {
    v2f d;
    asm("v_pk_add_f32 %0, %1, %2 op_sel:[0,1] op_sel_hi:[0,1] neg_hi:[0,1]"
        : "=v"(d) : "v"(a), "v"(a));
    return d;
}
__device__ __forceinline__ v2f pkadd(v2f a, v2f b) {
    v2f d;
    asm("v_pk_add_f32 %0, %1, %2" : "=v"(d) : "v"(a), "v"(b));
    return d;
}
__device__ __forceinline__ v2f pksub(v2f a, v2f b) {
    v2f d;
    asm("v_pk_add_f32 %0, %1, %2 neg_lo:[0,1] neg_hi:[0,1]"
        : "=v"(d) : "v"(a), "v"(b));
    return d;
}
__device__ __forceinline__ v2f pkmul(v2f a, v2f b) {
    v2f d;
    asm("v_pk_mul_f32 %0, %1, %2" : "=v"(d) : "v"(a), "v"(b));
    return d;
}

// In-register FWHT over 4 index bits (16 values held as 8 packed v2f).
// w[p] = (v[2p], v[2p+1]); stage 0 = intra-pair, stages 1-3 = inter-pair.
__device__ __forceinline__ void radix16(v2f w[8]) {
#pragma unroll
    for (int p = 0; p < 8; ++p) w[p] = bfly0(w[p]);
#pragma unroll
    for (int s = 0; s < 3; ++s) {
        const int d = 1 << s;
#pragma unroll
        for (int p = 0; p < 8; ++p) {
            if (!(p & d)) {
                const v2f a = w[p];
                const v2f b = w[p + d];
                w[p]     = pkadd(a, b);
                w[p + d] = pksub(a, b);
            }
        }
    }
}

__global__ void compute_u_kernel(const float* __restrict__ g_mu,
                                 const float* __restrict__ g_rho,
                                 const float* __restrict__ eps,
                                 float* __restrict__ u) {
    const int i = blockIdx.x * blockDim.x + threadIdx.x;
    if (i < D_DIM) {
        const float r = g_rho[i];
        const float sp = (r > 20.0f) ? r : log1pf(expf(r));  // softplus
        // fold the 1/sqrt(D)/sqrt(D) = 1/64 FWHT normalization in here
        u[i] = (g_mu[i] + sp * eps[i]) * 0.015625f;
    }
}

__global__ __launch_bounds__(256) void whvi_kernel(const float* __restrict__ x,
                                                   const float* __restrict__ s1,
                                                   const float* __restrict__ s2,
                                                   const float* __restrict__ u,
                                                   float* __restrict__ out) {
    __shared__ float lds[D_DIM];
    const int t = threadIdx.x;
    const int row = blockIdx.x;
    const float* __restrict__ xr = x + (size_t)row * D_DIM;

    v2f w[8];

    // ---- P0: coalesced load x*s2 (e = t + 256m), FWHT bits 8-11, LDS write ----
#pragma unroll
    for (int p = 0; p < 8; ++p) {
        const int e0 = t + ((2 * p) << 8);
        const int e1 = t + ((2 * p + 1) << 8);
        w[p] = (v2f){xr[e0] * s2[e0], xr[e1] * s2[e1]};
    }
    radix16(w);
#pragma unroll
    for (int p = 0; p < 8; ++p) {
        lds[swz(t + ((2 * p) << 8))]     = w[p].x;
        lds[swz(t + ((2 * p + 1) << 8))] = w[p].y;
    }
    __syncthreads();

    // ---- P1: FWHT bits 4-7 (in-place; per-thread address set is private) ----
    {
        const int base = ((t >> 4) << 8) | (t & 15);
#pragma unroll
        for (int p = 0; p < 8; ++p) {
            w[p].x = lds[swz(base | ((2 * p) << 4))];
            w[p].y = lds[swz(base | ((2 * p + 1) << 4))];
        }
        radix16(w);
#pragma unroll
        for (int p = 0; p < 8; ++p) {
            lds[swz(base | ((2 * p) << 4))]     = w[p].x;
            lds[swz(base | ((2 * p + 1) << 4))] = w[p].y;
        }
    }
    __syncthreads();

    // ---- P2: FWHT bits 0-3, * u, FWHT bits 0-3 (fused; contiguous b128) ----
    {
        const int base = t << 4;
#pragma unroll
        for (int g = 0; g < 4; ++g) {
            const float4 r = *reinterpret_cast<const float4*>(&lds[swz(base | (g << 2))]);
            w[2 * g]     = (v2f){r.x, r.y};
            w[2 * g + 1] = (v2f){r.z, r.w};
        }
        radix16(w);
        const v2f* __restrict__ u2 = reinterpret_cast<const v2f*>(u + base);
#pragma unroll
        for (int p = 0; p < 8; ++p) w[p] = pkmul(w[p], u2[p]);
        radix16(w);
#pragma unroll
        for (int g = 0; g < 4; ++g) {
            const float4 f = make_float4(w[2 * g].x, w[2 * g].y,
                                         w[2 * g + 1].x, w[2 * g + 1].y);
            *reinterpret_cast<float4*>(&lds[swz(base | (g << 2))]) = f;
        }
    }
    __syncthreads();

    // ---- P3: FWHT bits 4-7 ----
    {
        const int base = ((t >> 4) << 8) | (t & 15);
#pragma unroll
        for (int p = 0; p < 8; ++p) {
            w[p].x = lds[swz(base | ((2 * p) << 4))];
            w[p].y = lds[swz(base | ((2 * p + 1) << 4))];
        }
        radix16(w);
#pragma unroll
        for (int p = 0; p < 8; ++p) {
            lds[swz(base | ((2 * p) << 4))]     = w[p].x;
            lds[swz(base | ((2 * p + 1) << 4))] = w[p].y;
        }
    }
    __syncthreads();

    // ---- P4: FWHT bits 8-11, * s1, coalesced store ----
#pragma unroll
    for (int p = 0; p < 8; ++p) {
        w[p].x = lds[swz(t + ((2 * p) << 8))];
        w[p].y = lds[swz(t + ((2 * p + 1) << 8))];
    }
    radix16(w);
    float* __restrict__ orow = out + (size_t)row * D_DIM;
#pragma unroll
    for (int p = 0; p < 8; ++p) {
        const int e0 = t + ((2 * p) << 8);
        const int e1 = t + ((2 * p + 1) << 8);
        orow[e0] = w[p].x * s1[e0];
        orow[e1] = w[p].y * s1[e1];
    }
}

extern "C" void kernel_launch(void* const* d_in, const int* in_sizes, int n_in,
                              void* d_out, int out_size, void* d_ws, size_t ws_size,
                              hipStream_t stream) {
    const float* x     = (const float*)d_in[0];
    const float* s1    = (const float*)d_in[1];
    const float* s2    = (const float*)d_in[2];
    const float* g_mu  = (const float*)d_in[3];
    const float* g_rho = (const float*)d_in[4];
    const float* eps   = (const float*)d_in[5];
    // d_in[6] = H : realized implicitly by the FWHT butterflies.

    float* u   = (float*)d_ws;   // D floats of scratch
    float* out = (float*)d_out;

    const int N = in_sizes[0] / D_DIM;

    compute_u_kernel<<<(D_DIM + 255) / 256, 256, 0, stream>>>(g_mu, g_rho, eps, u);
    whvi_kernel<<<N, 256, 0, stream>>>(x, s1, s2, u, out);
}

// Round 3
// 132.517 us; speedup vs baseline: 1.1000x; 1.0433x over previous
//
#include <hip/hip_runtime.h>
#include <math.h>

#define D_DIM 4096

typedef float v2f __attribute__((ext_vector_type(2)));

// ---- packed-f32 butterfly primitives (VOP3P) ----
// bfly0: d = (a.x + a.y, a.x - a.y) -- one instruction for a bit-0 butterfly.
__device__ __forceinline__ v2f bfly0(v2f a) {
    v2f d;
    asm("v_pk_add_f32 %0, %1, %2 op_sel:[0,1] op_sel_hi:[0,1] neg_hi:[0,1]"
        : "=v"(d) : "v"(a), "v"(a));
    return d;
}
__device__ __forceinline__ v2f pkadd(v2f a, v2f b) {
    v2f d;
    asm("v_pk_add_f32 %0, %1, %2" : "=v"(d) : "v"(a), "v"(b));
    return d;
}
__device__ __forceinline__ v2f pksub(v2f a, v2f b) {
    v2f d;
    asm("v_pk_add_f32 %0, %1, %2 neg_lo:[0,1] neg_hi:[0,1]"
        : "=v"(d) : "v"(a), "v"(b));
    return d;
}
__device__ __forceinline__ v2f pkmul(v2f a, v2f b) {
    v2f d;
    asm("v_pk_mul_f32 %0, %1, %2" : "=v"(d) : "v"(a), "v"(b));
    return d;
}

// In-register FWHT over 6 index bits: 64 values held as 32 packed v2f.
// w[p] = (val[2p], val[2p+1]). Stage 0 intra-pair (bfly0), stages 1-5 inter.
__device__ __forceinline__ void radix64(v2f w[32]) {
#pragma unroll
    for (int p = 0; p < 32; ++p) w[p] = bfly0(w[p]);
#pragma unroll
    for (int s = 0; s < 5; ++s) {
        const int d = 1 << s;
#pragma unroll
        for (int p = 0; p < 32; ++p) {
            if (!(p & d)) {
                const v2f a = w[p];
                const v2f b = w[p + d];
                w[p]     = pkadd(a, b);
                w[p + d] = pksub(a, b);
            }
        }
    }
}

// u_perm[l*64 + m] = u[e]/64 where e = (l>>2)*256 + m*4 + (l&3):
// exactly the element phase-B lane l holds at register index m, so the
// mid-pipeline multiply is a contiguous b128 load.
__global__ void compute_u_kernel(const float* __restrict__ g_mu,
                                 const float* __restrict__ g_rho,
                                 const float* __restrict__ eps,
                                 float* __restrict__ u_perm) {
    const int j = blockIdx.x * blockDim.x + threadIdx.x;  // j = l*64 + m
    if (j < D_DIM) {
        const int e = ((j >> 8) << 8) | ((j & 63) << 2) | ((j >> 6) & 3);
        const float r = g_rho[e];
        const float sp = (r > 20.0f) ? r : log1pf(expf(r));  // softplus
        // fold the 1/sqrt(D)*1/sqrt(D) = 1/64 normalization here
        u_perm[j] = (g_mu[e] + sp * eps[e]) * 0.015625f;
    }
}

// One row (4096 floats) per 64-thread (1-wave) workgroup.
// e-bit split: phase A/A' hold bits {0,1,8..11} in-register (q = e[0:1],
// r = e[8:11], reg v = 4r+q), lane = e[2:7]. Phase B holds bits {2..7}
// in-register (reg m), lane l' = v. 64x64 lane-transpose via LDS:
//   layout: value (lane, reg) at word  reg*64 + (lane ^ 4*(reg&15))
//   -> writes (fixed reg per instr): banks (lane^c)&31 = 2-way (free)
//   -> reads at pre-swizzled addr l*64 + 4*(k ^ (l&15)): returns content
//      m = 4k+i unpermuted, 4 lanes per bank-quad = optimal 8-cyc b128.
__global__ __launch_bounds__(64) void whvi_kernel(const float* __restrict__ x,
                                                  const float* __restrict__ s1,
                                                  const float* __restrict__ s2,
                                                  const float* __restrict__ u_perm,
                                                  float* __restrict__ out) {
    __shared__ float lds[D_DIM];
    const int l = threadIdx.x;  // 0..63
    const float* __restrict__ xr = x + (size_t)blockIdx.x * D_DIM;

    v2f w[32];

    // ---- Phase A: coalesced b128 loads of x and s2, FWHT bits {0,1,8..11} ----
#pragma unroll
    for (int r = 0; r < 16; ++r) {
        const int off = (r << 8) + (l << 2);  // e = 256r + 4l + q
        const float4 xv = *reinterpret_cast<const float4*>(xr + off);
        const float4 sv = *reinterpret_cast<const float4*>(s2 + off);
        w[2 * r]     = pkmul((v2f){xv.x, xv.y}, (v2f){sv.x, sv.y});
        w[2 * r + 1] = pkmul((v2f){xv.z, xv.w}, (v2f){sv.z, sv.w});
    }
    radix64(w);

    // ---- Transpose 1: write (b32, 2-way free) ----
#pragma unroll
    for (int v = 0; v < 64; ++v) {
        const float val = (v & 1) ? w[v >> 1].y : w[v >> 1].x;
        lds[(v << 6) + (l ^ ((v & 15) << 2))] = val;
    }
    __syncthreads();

    const int L4 = (l & 15) << 2;
    const int rbase = l << 6;

    // ---- Phase B: b128 swizzled reads, FWHT bits {2..7}, *u, FWHT bits {2..7} ----
#pragma unroll
    for (int k = 0; k < 16; ++k) {
        const float4 f = *reinterpret_cast<const float4*>(&lds[rbase + (((k << 2)) ^ L4)]);
        w[2 * k]     = (v2f){f.x, f.y};
        w[2 * k + 1] = (v2f){f.z, f.w};
    }
    radix64(w);
    const v2f* __restrict__ up = reinterpret_cast<const v2f*>(u_perm + rbase);
#pragma unroll
    for (int p = 0; p < 32; ++p) w[p] = pkmul(w[p], up[p]);
    radix64(w);
    __syncthreads();  // all lanes done reading T1 before overwrite

    // ---- Transpose 2: write back (roles of lane/reg swapped) ----
#pragma unroll
    for (int m = 0; m < 64; ++m) {
        const float val = (m & 1) ? w[m >> 1].y : w[m >> 1].x;
        lds[(m << 6) + (l ^ ((m & 15) << 2))] = val;
    }
    __syncthreads();

    // ---- Phase A': b128 swizzled reads, FWHT bits {0,1,8..11}, *s1, store ----
#pragma unroll
    for (int k = 0; k < 16; ++k) {
        const float4 f = *reinterpret_cast<const float4*>(&lds[rbase + ((k << 2) ^ L4)]);
        w[2 * k]     = (v2f){f.x, f.y};
        w[2 * k + 1] = (v2f){f.z, f.w};
    }
    radix64(w);

    float* __restrict__ orow = out + (size_t)blockIdx.x * D_DIM;
#pragma unroll
    for (int r = 0; r < 16; ++r) {
        const int off = (r << 8) + (l << 2);
        const float4 sv = *reinterpret_cast<const float4*>(s1 + off);
        const v2f o0 = pkmul(w[2 * r],     (v2f){sv.x, sv.y});
        const v2f o1 = pkmul(w[2 * r + 1], (v2f){sv.z, sv.w});
        *reinterpret_cast<float4*>(orow + off) = make_float4(o0.x, o0.y, o1.x, o1.y);
    }
}

extern "C" void kernel_launch(void* const* d_in, const int* in_sizes, int n_in,
                              void* d_out, int out_size, void* d_ws, size_t ws_size,
                              hipStream_t stream) {
    const float* x     = (const float*)d_in[0];
    const float* s1    = (const float*)d_in[1];
    const float* s2    = (const float*)d_in[2];
    const float* g_mu  = (const float*)d_in[3];
    const float* g_rho = (const float*)d_in[4];
    const float* eps   = (const float*)d_in[5];
    // d_in[6] = H : realized implicitly by the FWHT butterflies.

    float* u_perm = (float*)d_ws;  // D floats of scratch (permuted, pre-scaled u)
    float* out    = (float*)d_out;

    const int N = in_sizes[0] / D_DIM;

    compute_u_kernel<<<(D_DIM + 255) / 256, 256, 0, stream>>>(g_mu, g_rho, eps, u_perm);
    whvi_kernel<<<N, 64, 0, stream>>>(x, s1, s2, u_perm, out);
}

// Round 4
// 125.752 us; speedup vs baseline: 1.1592x; 1.0538x over previous
//
#include <hip/hip_runtime.h>
#include <math.h>

#define D_DIM 4096
#define ROWS_PER_WG 8

typedef float v2f __attribute__((ext_vector_type(2)));

// ---- packed-f32 butterfly primitives (VOP3P) ----
__device__ __forceinline__ v2f bfly0(v2f a) {
    v2f d;
    asm("v_pk_add_f32 %0, %1, %2 op_sel:[0,1] op_sel_hi:[0,1] neg_hi:[0,1]"
        : "=v"(d) : "v"(a), "v"(a));
    return d;
}
__device__ __forceinline__ v2f pkadd(v2f a, v2f b) {
    v2f d;
    asm("v_pk_add_f32 %0, %1, %2" : "=v"(d) : "v"(a), "v"(b));
    return d;
}
__device__ __forceinline__ v2f pksub(v2f a, v2f b) {
    v2f d;
    asm("v_pk_add_f32 %0, %1, %2 neg_lo:[0,1] neg_hi:[0,1]"
        : "=v"(d) : "v"(a), "v"(b));
    return d;
}
__device__ __forceinline__ v2f pkmul(v2f a, v2f b) {
    v2f d;
    asm("v_pk_mul_f32 %0, %1, %2" : "=v"(d) : "v"(a), "v"(b));
    return d;
}

// In-register FWHT over 6 bits: 64 values as 32 packed v2f.
__device__ __forceinline__ void radix64(v2f w[32]) {
#pragma unroll
    for (int p = 0; p < 32; ++p) w[p] = bfly0(w[p]);
#pragma unroll
    for (int s = 0; s < 5; ++s) {
        const int d = 1 << s;
#pragma unroll
        for (int p = 0; p < 32; ++p) {
            if (!(p & d)) {
                const v2f a = w[p];
                const v2f b = w[p + d];
                w[p]     = pkadd(a, b);
                w[p + d] = pksub(a, b);
            }
        }
    }
}

// async global->LDS, 16 B per lane; LDS dest = uniform base + lane*16.
__device__ __forceinline__ void gload_lds16(const float* g, float* lp) {
    __builtin_amdgcn_global_load_lds(
        (const __attribute__((address_space(1))) void*)g,
        (__attribute__((address_space(3))) void*)lp, 16, 0, 0);
}

// opaque pointer copy: blocks LICM/CSE from persisting per-row reloads.
__device__ __forceinline__ const float* launder_ptr(const float* p) {
    asm volatile("" : "+s"(p));
    return p;
}

// u_perm[l*64 + m] = u[e]/64, e = (l>>2)*256 + m*4 + (l&3)  (B-layout).
__global__ void compute_u_kernel(const float* __restrict__ g_mu,
                                 const float* __restrict__ g_rho,
                                 const float* __restrict__ eps,
                                 float* __restrict__ u_perm) {
    const int j = blockIdx.x * blockDim.x + threadIdx.x;
    if (j < D_DIM) {
        const int e = ((j >> 8) << 8) | ((j & 63) << 2) | ((j >> 6) & 3);
        const float r = g_rho[e];
        const float sp = (r > 20.0f) ? r : log1pf(expf(r));
        u_perm[j] = (g_mu[e] + sp * eps[e]) * 0.015625f;
    }
}

// One wave per WG; ROWS_PER_WG rows per wave, software-pipelined:
//  - glds prefetch of row r+1 issued after row r's last LDS read
//  - no __syncthreads (single-wave LDS ordering via lgkm deps)
//  - one counted s_waitcnt vmcnt(24) per row: in-order vmcnt retirement
//    => forces exactly the 16 glds ops (oldest), leaves stores(16)+s2a(8).
__global__ __launch_bounds__(64, 2) void whvi_kernel(const float* __restrict__ x,
                                                     const float* __restrict__ s1,
                                                     const float* __restrict__ s2,
                                                     const float* __restrict__ u_perm,
                                                     float* __restrict__ out,
                                                     int nrows) {
    __shared__ float lds[D_DIM];
    const int l = threadIdx.x;
    const int row0 = blockIdx.x * ROWS_PER_WG;
    if (row0 >= nrows) return;
    const int rend = min(row0 + ROWS_PER_WG, nrows);

    const int l4 = l << 2;
    const int L4 = (l & 15) << 2;
    const int rbase = l << 6;

    // ---- prologue: prefetch row0 (oldest vmem ops), then persistent u ----
    {
        const float* xr = x + (size_t)row0 * D_DIM;
#pragma unroll
        for (int k = 0; k < 16; ++k)
            gload_lds16(xr + (k << 8) + l4, &lds[k << 8]);
    }
    v2f u2[32];
    {
        const v2f* up = reinterpret_cast<const v2f*>(u_perm + rbase);
#pragma unroll
        for (int p = 0; p < 32; ++p) u2[p] = up[p];
    }

    v2f w[32];

    for (int row = row0; row < rend; ++row) {
        // ---- Phase A: s2 chunk loads + wait prefetch + FWHT bits {0,1,8..11} ----
        const float* s2p = launder_ptr(s2);
        float4 s2a[8];
#pragma unroll
        for (int k = 0; k < 8; ++k)
            s2a[k] = *reinterpret_cast<const float4*>(s2p + (k << 8) + l4);

        // force the 16 glds of this row (oldest); steady-state leaves exactly
        // stores(r-1)=16 + s2a=8 outstanding.
        asm volatile("s_waitcnt vmcnt(24)" ::: "memory");
        __builtin_amdgcn_sched_barrier(0);

#pragma unroll
        for (int k = 0; k < 8; ++k) {
            const float4 xv = *reinterpret_cast<const float4*>(&lds[(k << 8) + l4]);
            w[2 * k]     = pkmul((v2f){xv.x, xv.y}, (v2f){s2a[k].x, s2a[k].y});
            w[2 * k + 1] = pkmul((v2f){xv.z, xv.w}, (v2f){s2a[k].z, s2a[k].w});
        }
        float4 s2b[8];
#pragma unroll
        for (int k = 0; k < 8; ++k)
            s2b[k] = *reinterpret_cast<const float4*>(s2p + ((k + 8) << 8) + l4);
#pragma unroll
        for (int k = 0; k < 8; ++k) {
            const float4 xv = *reinterpret_cast<const float4*>(&lds[((k + 8) << 8) + l4]);
            w[2 * (k + 8)]     = pkmul((v2f){xv.x, xv.y}, (v2f){s2b[k].x, s2b[k].y});
            w[2 * (k + 8) + 1] = pkmul((v2f){xv.z, xv.w}, (v2f){s2b[k].z, s2b[k].w});
        }
        radix64(w);

        // ---- Transpose 1 (b32 writes, <=2-way banks: free) ----
#pragma unroll
        for (int v = 0; v < 64; ++v) {
            const float val = (v & 1) ? w[v >> 1].y : w[v >> 1].x;
            lds[(v << 6) + (l ^ ((v & 15) << 2))] = val;
        }

        // ---- Phase B: FWHT bits {2..7}, *u, FWHT bits {2..7} ----
#pragma unroll
        for (int k = 0; k < 16; ++k) {
            const float4 f = *reinterpret_cast<const float4*>(&lds[rbase + ((k << 2) ^ L4)]);
            w[2 * k]     = (v2f){f.x, f.y};
            w[2 * k + 1] = (v2f){f.z, f.w};
        }
        radix64(w);
#pragma unroll
        for (int p = 0; p < 32; ++p) w[p] = pkmul(w[p], u2[p]);
        radix64(w);

        // ---- Transpose 2 ----
#pragma unroll
        for (int m = 0; m < 64; ++m) {
            const float val = (m & 1) ? w[m >> 1].y : w[m >> 1].x;
            lds[(m << 6) + (l ^ ((m & 15) << 2))] = val;
        }

        // s1 loads issued BEFORE the next glds so consuming s1 never drains it
        const float* s1p = launder_ptr(s1);
        float4 s1v[16];
#pragma unroll
        for (int k = 0; k < 16; ++k)
            s1v[k] = *reinterpret_cast<const float4*>(s1p + (k << 8) + l4);

        // ---- Phase A' reads (last use of the buffer for this row) ----
        float4 fv[16];
#pragma unroll
        for (int k = 0; k < 16; ++k)
            fv[k] = *reinterpret_cast<const float4*>(&lds[rbase + ((k << 2) ^ L4)]);

        // ---- prefetch next row into the now-dead buffer ----
        if (row + 1 < rend) {
            const float* xr = x + (size_t)(row + 1) * D_DIM;
#pragma unroll
            for (int k = 0; k < 16; ++k)
                gload_lds16(xr + (k << 8) + l4, &lds[k << 8]);
            asm volatile("" ::: "memory");  // pin [glds][stores] issue order
        }

#pragma unroll
        for (int k = 0; k < 16; ++k) {
            w[2 * k]     = (v2f){fv[k].x, fv[k].y};
            w[2 * k + 1] = (v2f){fv[k].z, fv[k].w};
        }
        radix64(w);

        // ---- scale by s1, coalesced store ----
        float* orow = out + (size_t)row * D_DIM;
#pragma unroll
        for (int r = 0; r < 16; ++r) {
            const v2f o0 = pkmul(w[2 * r],     (v2f){s1v[r].x, s1v[r].y});
            const v2f o1 = pkmul(w[2 * r + 1], (v2f){s1v[r].z, s1v[r].w});
            *reinterpret_cast<float4*>(orow + (r << 8) + l4) =
                make_float4(o0.x, o0.y, o1.x, o1.y);
        }
    }
}

extern "C" void kernel_launch(void* const* d_in, const int* in_sizes, int n_in,
                              void* d_out, int out_size, void* d_ws, size_t ws_size,
                              hipStream_t stream) {
    const float* x     = (const float*)d_in[0];
    const float* s1    = (const float*)d_in[1];
    const float* s2    = (const float*)d_in[2];
    const float* g_mu  = (const float*)d_in[3];
    const float* g_rho = (const float*)d_in[4];
    const float* eps   = (const float*)d_in[5];
    // d_in[6] = H : realized implicitly by the FWHT butterflies.

    float* u_perm = (float*)d_ws;
    float* out    = (float*)d_out;

    const int N = in_sizes[0] / D_DIM;
    const int nwg = (N + ROWS_PER_WG - 1) / ROWS_PER_WG;

    compute_u_kernel<<<(D_DIM + 255) / 256, 256, 0, stream>>>(g_mu, g_rho, eps, u_perm);
    whvi_kernel<<<nwg, 64, 0, stream>>>(x, s1, s2, u_perm, out, N);
}